// Round 4
// baseline (39.567 us; speedup 1.0000x reference)
//
#include <hip/hip_runtime.h>
#include <hip/hip_bf16.h>

#define PN 2048

typedef __attribute__((ext_vector_type(8))) short short8;
typedef __attribute__((ext_vector_type(4))) float f32x4;

static __device__ __forceinline__ unsigned int pk_bf2(float lo, float hi) {
    unsigned int ul = __float_as_uint(lo);
    unsigned int uh = __float_as_uint(hi);
    ul = (ul + 0x7fffu + ((ul >> 16) & 1u)) >> 16;   // RNE f32->bf16
    uh = (uh + 0x7fffu + ((uh >> 16) & 1u)) >> 16;
    return ul | (uh << 16);
}

// ws layout: Ebf uint[2048*128] (bf16 even rows), Obf uint[2048*128] (odd rows),
//            Spart float[2*16][2048], Dpos float[2048]

__global__ __launch_bounds__(256) void sml_convert(
    const float* __restrict__ X, unsigned int* __restrict__ E, unsigned int* __restrict__ O)
{
    const int idx = blockIdx.x * 256 + threadIdx.x;   // 131072 threads, 8 floats each
    const int m = idx >> 16;            // 0: even rows, 1: odd rows
    const int e = idx & 65535;
    const int p = e >> 5;               // pair index 0..2047
    const int c = e & 31;               // 8-float chunk within row
    const float* src = X + (size_t)(2 * p + m) * 256 + c * 8;
    const float4 v0 = *(const float4*)(src);
    const float4 v1 = *(const float4*)(src + 4);
    uint4 w = { pk_bf2(v0.x, v0.y), pk_bf2(v0.z, v0.w),
                pk_bf2(v1.x, v1.y), pk_bf2(v1.z, v1.w) };
    unsigned int* dst = (m ? O : E) + p * 128 + c * 4;
    *(uint4*)dst = w;
}

__global__ __launch_bounds__(256, 2) void sml_mfma(
    const unsigned int* __restrict__ Ebf, const unsigned int* __restrict__ Obf,
    float* __restrict__ Spart, float* __restrict__ Dpos)
{
    __shared__ __align__(16) unsigned int A_s[128 * 32];  // bf16[row][64], 16B-slot XOR-swizzled
    __shared__ __align__(16) unsigned int B_s[128 * 32];
    __shared__ float S_red[2][128];

    const int bx = blockIdx.x, by = blockIdx.y, gemm = blockIdx.z;
    const int t = threadIdx.x;
    const int lane = t & 63, wid = t >> 6;
    const int wr = wid >> 1, wc = wid & 1;

    const unsigned int* Abase = gemm ? Obf : Ebf;
    const unsigned int* Bbase = gemm ? Ebf : Obf;

    // staging: thread handles 16B slot s (8 bf16) of rows r0+32q (q=0..3), A and B
    const int s  = t & 7;
    const int r0 = t >> 3;

    const unsigned int* aptr[4];
    const unsigned int* bptr[4];
    #pragma unroll
    for (int q = 0; q < 4; ++q) {
        const int r = r0 + 32 * q;
        aptr[q] = Abase + (size_t)(bx * 128 + r) * 128 + s * 4;
        bptr[q] = Bbase + (size_t)(by * 128 + r) * 128 + s * 4;
    }

    f32x4 acc[4][4];
    #pragma unroll
    for (int i = 0; i < 4; ++i)
        #pragma unroll
        for (int j = 0; j < 4; ++j) acc[i][j] = (f32x4){0.f, 0.f, 0.f, 0.f};

    uint4 pa[4], pb[4];
    #pragma unroll
    for (int q = 0; q < 4; ++q) {
        pa[q] = *(const uint4*)(aptr[q]);
        pb[q] = *(const uint4*)(bptr[q]);
    }

    const int g4 = lane >> 4;   // k-group 0..3
    const int rl = lane & 15;

    for (int ks = 0; ks < 4; ++ks) {
        __syncthreads();   // previous chunk's LDS reads done
        #pragma unroll
        for (int q = 0; q < 4; ++q) {
            const int r  = r0 + 32 * q;
            const int sw = (s ^ (r & 7)) << 2;
            *(uint4*)&A_s[r * 32 + sw] = pa[q];
            *(uint4*)&B_s[r * 32 + sw] = pb[q];
        }
        __syncthreads();
        if (ks < 3) {   // prefetch next chunk into regs; consumed after next barrier
            const int off = (ks + 1) * 32;
            #pragma unroll
            for (int q = 0; q < 4; ++q) {
                pa[q] = *(const uint4*)(aptr[q] + off);
                pb[q] = *(const uint4*)(bptr[q] + off);
            }
        }
        #pragma unroll
        for (int kk = 0; kk < 2; ++kk) {
            short8 af[4], bfj[4];
            #pragma unroll
            for (int i = 0; i < 4; ++i) {
                const int r  = wr * 64 + i * 16 + rl;
                const int sl = (kk * 4 + g4) ^ (r & 7);
                af[i] = *(const short8*)&A_s[r * 32 + sl * 4];
            }
            #pragma unroll
            for (int j = 0; j < 4; ++j) {
                const int r  = wc * 64 + j * 16 + rl;
                const int sl = (kk * 4 + g4) ^ (r & 7);
                bfj[j] = *(const short8*)&B_s[r * 32 + sl * 4];
            }
            #pragma unroll
            for (int i = 0; i < 4; ++i)
                #pragma unroll
                for (int j = 0; j < 4; ++j)
                    acc[i][j] = __builtin_amdgcn_mfma_f32_16x16x32_bf16(af[i], bfj[j], acc[i][j], 0, 0, 0);
        }
    }

    // fused epilogue: exp(1 + c/128), mask k==excl, extract Dpos (gemm 0 diagonal), row-reduce
    const int prow_base = bx * 128 + wr * 64;
    const int kcol_base = by * 128 + wc * 64;
    float rs[4][4];
    #pragma unroll
    for (int i = 0; i < 4; ++i)
        #pragma unroll
        for (int rg = 0; rg < 4; ++rg) rs[i][rg] = 0.f;

    #pragma unroll
    for (int i = 0; i < 4; ++i) {
        #pragma unroll
        for (int j = 0; j < 4; ++j) {
            const int k = kcol_base + j * 16 + rl;       // C/D: col = lane&15 [m89]
            #pragma unroll
            for (int rg = 0; rg < 4; ++rg) {
                const int p = prow_base + i * 16 + g4 * 4 + rg;   // row = (lane>>4)*4 + reg
                const float c = acc[i][j][rg] * (1.f / 128.f);
                if (gemm == 0 && k == p) Dpos[p] = c;             // D[2p,2p+1]
                float e = __expf(1.f + c);
                const int excl = (gemm == 0) ? (2 * p + 1) : (2 * p);
                if (k == excl) e = 0.f;
                rs[i][rg] += e;
            }
        }
    }
    #pragma unroll
    for (int i = 0; i < 4; ++i) {
        #pragma unroll
        for (int rg = 0; rg < 4; ++rg) {
            float v = rs[i][rg];
            v += __shfl_xor(v, 1); v += __shfl_xor(v, 2);
            v += __shfl_xor(v, 4); v += __shfl_xor(v, 8);
            if (rl == 0) S_red[wc][wr * 64 + i * 16 + g4 * 4 + rg] = v;
        }
    }
    __syncthreads();
    if (t < 128)
        Spart[(gemm * 16 + by) * PN + bx * 128 + t] = S_red[0][t] + S_red[1][t];
}

__global__ __launch_bounds__(1024) void sml_finish(
    const float* __restrict__ Spart, const float* __restrict__ Dpos, float* __restrict__ out)
{
    __shared__ float red[16];
    const int t = threadIdx.x;
    float local = 0.f;
    for (int p = t; p < PN; p += 1024) {
        float ssum = 0.f;
        #pragma unroll
        for (int g = 0; g < 32; ++g) ssum += Spart[g * PN + p];
        const float J = __logf(1e-8f + ssum) - Dpos[p];
        const float v = fmaxf(J, 0.f);
        local += v * v;
    }
    #pragma unroll
    for (int m = 1; m < 64; m <<= 1) local += __shfl_xor(local, m);
    if ((t & 63) == 0) red[t >> 6] = local;
    __syncthreads();
    if (t == 0) {
        float ssum = 0.f;
        #pragma unroll
        for (int w = 0; w < 16; ++w) ssum += red[w];
        out[0] = ssum * (1.f / 4096.f);
    }
}

extern "C" void kernel_launch(void* const* d_in, const int* in_sizes, int n_in,
                              void* d_out, int out_size, void* d_ws, size_t ws_size,
                              hipStream_t stream) {
    const float* X = (const float*)d_in[0];
    unsigned int* Ebf = (unsigned int*)d_ws;          // 2048*128 uints
    unsigned int* Obf = Ebf + 2048 * 128;             // 2048*128 uints
    float* Spart = (float*)(Obf + 2048 * 128);        // 32 * 2048 floats
    float* Dpos  = Spart + 32 * PN;                   // 2048 floats
    float* out   = (float*)d_out;

    sml_convert<<<512, 256, 0, stream>>>(X, Ebf, Obf);
    dim3 g1(16, 16, 2);
    sml_mfma<<<g1, dim3(256), 0, stream>>>(Ebf, Obf, Spart, Dpos);
    sml_finish<<<1, dim3(1024), 0, stream>>>(Spart, Dpos, out);
}

// Round 5
// 19.836 us; speedup vs baseline: 1.9947x; 1.9947x over previous
//
#include <hip/hip_runtime.h>

#define PN 2048

typedef __attribute__((ext_vector_type(8))) short short8;
typedef __attribute__((ext_vector_type(4))) float f32x4;

static __device__ __forceinline__ unsigned int pk_bf2(float lo, float hi) {
    unsigned int ul = __float_as_uint(lo);
    unsigned int uh = __float_as_uint(hi);
    ul = (ul + 0x7fffu + ((ul >> 16) & 1u)) >> 16;   // RNE f32->bf16
    uh = (uh + 0x7fffu + ((uh >> 16) & 1u)) >> 16;
    return ul | (uh << 16);
}

// ws layout (floats): Srow[16][2048], Scol[16][2048], Dpos[2048], Ex1[2048], Ex2[2048]
// Single GEMM: M[p,k] = dot(X[2p], X[2k+1])/128, T = exp(1+M).
// neg_ik[p] = rowsum(T)[p] - (p<1024 ? T[p,2p+1] : 0)
// neg_jl[p] = colsum(T)[p] - (p<1024 ? T[2p,p] : 0)
// Dpos[p]   = M[p,p]

__global__ __launch_bounds__(512, 2) void sml_mfma(
    const float* __restrict__ X, float* __restrict__ Srow, float* __restrict__ Scol,
    float* __restrict__ Dpos, float* __restrict__ Ex1, float* __restrict__ Ex2)
{
    __shared__ __align__(16) unsigned int A_s[128 * 32];  // bf16[row][64], 16B-slot XOR-swizzled
    __shared__ __align__(16) unsigned int B_s[128 * 32];
    __shared__ float red[4][128];

    const int bx = blockIdx.x, by = blockIdx.y;
    const int t = threadIdx.x;                 // 0..511, 8 waves
    const int lane = t & 63, wid = t >> 6;
    const int wr = wid >> 2, wc = wid & 3;     // wave grid 2 x 4 over (64-row x 32-col) subtiles
    const int g4 = lane >> 4, rl = lane & 15;

    // staging: thread handles 16B k-slot s of rows r0 + 64q (q=0,1), A (even rows) and B (odd rows)
    const int s  = t & 7;
    const int r0 = t >> 3;

    const float* aptr[2];
    const float* bptr[2];
    #pragma unroll
    for (int q = 0; q < 2; ++q) {
        const int r = r0 + 64 * q;
        aptr[q] = X + (size_t)(2 * (bx * 128 + r)) * 256 + s * 8;
        bptr[q] = X + (size_t)(2 * (by * 128 + r) + 1) * 256 + s * 8;
    }

    f32x4 acc[4][2];
    #pragma unroll
    for (int i = 0; i < 4; ++i)
        #pragma unroll
        for (int j = 0; j < 2; ++j) acc[i][j] = (f32x4){0.f, 0.f, 0.f, 0.f};

    float4 pa[2][2], pb[2][2];
    #pragma unroll
    for (int q = 0; q < 2; ++q) {
        pa[q][0] = *(const float4*)(aptr[q]);
        pa[q][1] = *(const float4*)(aptr[q] + 4);
        pb[q][0] = *(const float4*)(bptr[q]);
        pb[q][1] = *(const float4*)(bptr[q] + 4);
    }

    for (int ks = 0; ks < 4; ++ks) {
        __syncthreads();   // previous chunk's LDS reads done
        #pragma unroll
        for (int q = 0; q < 2; ++q) {
            const int r  = r0 + 64 * q;
            const int sw = (s ^ (r & 7)) << 2;
            uint4 wa = { pk_bf2(pa[q][0].x, pa[q][0].y), pk_bf2(pa[q][0].z, pa[q][0].w),
                         pk_bf2(pa[q][1].x, pa[q][1].y), pk_bf2(pa[q][1].z, pa[q][1].w) };
            uint4 wb = { pk_bf2(pb[q][0].x, pb[q][0].y), pk_bf2(pb[q][0].z, pb[q][0].w),
                         pk_bf2(pb[q][1].x, pb[q][1].y), pk_bf2(pb[q][1].z, pb[q][1].w) };
            *(uint4*)&A_s[r * 32 + sw] = wa;
            *(uint4*)&B_s[r * 32 + sw] = wb;
        }
        __syncthreads();
        if (ks < 3) {   // prefetch next fp32 chunk; consumed after next barrier
            const int off = (ks + 1) * 64;
            #pragma unroll
            for (int q = 0; q < 2; ++q) {
                pa[q][0] = *(const float4*)(aptr[q] + off);
                pa[q][1] = *(const float4*)(aptr[q] + off + 4);
                pb[q][0] = *(const float4*)(bptr[q] + off);
                pb[q][1] = *(const float4*)(bptr[q] + off + 4);
            }
        }
        #pragma unroll
        for (int kk = 0; kk < 2; ++kk) {
            short8 af[4], bfj[2];
            #pragma unroll
            for (int i = 0; i < 4; ++i) {
                const int r  = wr * 64 + i * 16 + rl;
                const int sl = (kk * 4 + g4) ^ (r & 7);
                af[i] = *(const short8*)&A_s[r * 32 + sl * 4];
            }
            #pragma unroll
            for (int j = 0; j < 2; ++j) {
                const int r  = wc * 32 + j * 16 + rl;
                const int sl = (kk * 4 + g4) ^ (r & 7);
                bfj[j] = *(const short8*)&B_s[r * 32 + sl * 4];
            }
            #pragma unroll
            for (int i = 0; i < 4; ++i)
                #pragma unroll
                for (int j = 0; j < 2; ++j)
                    acc[i][j] = __builtin_amdgcn_mfma_f32_16x16x32_bf16(af[i], bfj[j], acc[i][j], 0, 0, 0);
        }
    }

    // fused epilogue: e = exp(1 + c/128); row sums, col sums, Dpos/Ex1/Ex2 extraction
    float rs[4][4];
    float cs[2] = {0.f, 0.f};
    #pragma unroll
    for (int i = 0; i < 4; ++i)
        #pragma unroll
        for (int rg = 0; rg < 4; ++rg) rs[i][rg] = 0.f;

    #pragma unroll
    for (int i = 0; i < 4; ++i) {
        #pragma unroll
        for (int j = 0; j < 2; ++j) {
            const int kg = by * 128 + wc * 32 + j * 16 + rl;      // C/D: col = lane&15 [m89]
            #pragma unroll
            for (int rg = 0; rg < 4; ++rg) {
                const int pg = bx * 128 + wr * 64 + i * 16 + g4 * 4 + rg;  // row = (lane>>4)*4+reg
                const float c = acc[i][j][rg] * (1.f / 128.f);
                const float e = __expf(1.f + c);
                if (kg == pg) Dpos[pg] = c;            // M[p,p]
                if (kg == 2 * pg + 1) Ex1[pg] = e;     // T[p, 2p+1]
                if (pg == 2 * kg) Ex2[kg] = e;         // T[2k, k]
                rs[i][rg] += e;
                cs[j] += e;
            }
        }
    }

    // row reduction: sum over 16 cols (rl lanes) within each g4 group
    #pragma unroll
    for (int i = 0; i < 4; ++i) {
        #pragma unroll
        for (int rg = 0; rg < 4; ++rg) {
            float v = rs[i][rg];
            v += __shfl_xor(v, 1); v += __shfl_xor(v, 2);
            v += __shfl_xor(v, 4); v += __shfl_xor(v, 8);
            if (rl == 0) red[wc][wr * 64 + i * 16 + g4 * 4 + rg] = v;
        }
    }
    __syncthreads();
    if (t < 128)
        Srow[by * PN + bx * 128 + t] = red[0][t] + red[1][t] + red[2][t] + red[3][t];
    __syncthreads();   // before reusing red

    // col reduction: sum over g4 groups (64 rows per wave), then across wr waves via LDS
    #pragma unroll
    for (int j = 0; j < 2; ++j) {
        float v = cs[j];
        v += __shfl_xor(v, 16); v += __shfl_xor(v, 32);
        if (g4 == 0) red[wr][wc * 32 + j * 16 + rl] = v;
    }
    __syncthreads();
    if (t < 128)
        Scol[bx * PN + by * 128 + t] = red[0][t] + red[1][t];
}

__global__ __launch_bounds__(1024) void sml_finish(
    const float* __restrict__ Srow, const float* __restrict__ Scol,
    const float* __restrict__ Dpos, const float* __restrict__ Ex1,
    const float* __restrict__ Ex2, float* __restrict__ out)
{
    __shared__ float red[16];
    const int t = threadIdx.x;
    float local = 0.f;
    for (int p = t; p < PN; p += 1024) {
        float ssum = 0.f;
        #pragma unroll
        for (int g = 0; g < 16; ++g) ssum += Srow[g * PN + p];
        #pragma unroll
        for (int g = 0; g < 16; ++g) ssum += Scol[g * PN + p];
        if (p < 1024) ssum -= Ex1[p] + Ex2[p];
        const float J = __logf(1e-8f + ssum) - Dpos[p];
        const float v = fmaxf(J, 0.f);
        local += v * v;
    }
    #pragma unroll
    for (int m = 1; m < 64; m <<= 1) local += __shfl_xor(local, m);
    if ((t & 63) == 0) red[t >> 6] = local;
    __syncthreads();
    if (t == 0) {
        float ssum = 0.f;
        #pragma unroll
        for (int w = 0; w < 16; ++w) ssum += red[w];
        out[0] = ssum * (1.f / 4096.f);
    }
}

extern "C" void kernel_launch(void* const* d_in, const int* in_sizes, int n_in,
                              void* d_out, int out_size, void* d_ws, size_t ws_size,
                              hipStream_t stream) {
    const float* X = (const float*)d_in[0];
    float* ws   = (float*)d_ws;
    float* Srow = ws;                  // 16*2048
    float* Scol = Srow + 16 * PN;      // 16*2048
    float* Dpos = Scol + 16 * PN;      // 2048
    float* Ex1  = Dpos + PN;           // 2048
    float* Ex2  = Ex1 + PN;            // 2048
    float* out  = (float*)d_out;

    dim3 g1(16, 16);
    sml_mfma<<<g1, dim3(512), 0, stream>>>(X, Srow, Scol, Dpos, Ex1, Ex2);
    sml_finish<<<1, dim3(1024), 0, stream>>>(Srow, Scol, Dpos, Ex1, Ex2, out);
}

// Round 6
// 19.603 us; speedup vs baseline: 2.0185x; 1.0119x over previous
//
#include <hip/hip_runtime.h>

#define PN 2048

typedef __attribute__((ext_vector_type(8))) short short8;
typedef __attribute__((ext_vector_type(4))) float f32x4;

static __device__ __forceinline__ unsigned int pk_bf2(float lo, float hi) {
    unsigned int ul = __float_as_uint(lo);
    unsigned int uh = __float_as_uint(hi);
    ul = (ul + 0x7fffu + ((ul >> 16) & 1u)) >> 16;   // RNE f32->bf16
    uh = (uh + 0x7fffu + ((uh >> 16) & 1u)) >> 16;
    return ul | (uh << 16);
}

// Single GEMM: M[p,k] = dot(X[2p], X[2k+1])/128, T = exp(1+M).
// neg_ik[p] = rowsum(T)[p] - (p<1024 ? T[p,2p+1] : 0)
// neg_jl[p] = colsum(T)[p] - (p<1024 ? T[2p,p] : 0)
// Dpos[p]   = M[p,p]
// ws: Srow[32][2048], Scol[16][2048], Dpos[2048], Ex1[2048], Ex2[2048]
// Tile 128 rows x 64 cols, grid (16,32), 256 thr (4 waves), 2 blocks/CU.

__global__ __launch_bounds__(256, 2) void sml_mfma(
    const float* __restrict__ X, float* __restrict__ Srow, float* __restrict__ Scol,
    float* __restrict__ Dpos, float* __restrict__ Ex1, float* __restrict__ Ex2,
    float* __restrict__ out)
{
    __shared__ __align__(16) unsigned int A_s[128 * 32];  // bf16[128][64], 16B-slot XOR-swizzled
    __shared__ __align__(16) unsigned int B_s[64 * 32];   // bf16[64][64]
    __shared__ float red[2][128];
    __shared__ float red2[2][64];

    const int bx = blockIdx.x, by = blockIdx.y;
    const int t = threadIdx.x;                 // 0..255, 4 waves
    const int lane = t & 63, wid = t >> 6;
    const int wr = wid >> 1, wc = wid & 1;     // wave grid 2x2 over (64-row x 32-col) subtiles
    const int g4 = lane >> 4, rl = lane & 15;

    if (bx == 0 && by == 0 && t == 0) out[0] = 0.f;   // finish kernel accumulates atomically

    // staging: thread handles 16B k-slot s of A rows r0+32q (q<4) and B rows r0+32q (q<2)
    const int s  = t & 7;
    const int r0 = t >> 3;

    const float* aptr[4];
    const float* bptr[2];
    #pragma unroll
    for (int q = 0; q < 4; ++q)
        aptr[q] = X + (size_t)(2 * (bx * 128 + r0 + 32 * q)) * 256 + s * 8;
    #pragma unroll
    for (int q = 0; q < 2; ++q)
        bptr[q] = X + (size_t)(2 * (by * 64 + r0 + 32 * q) + 1) * 256 + s * 8;

    f32x4 acc[4][2];
    #pragma unroll
    for (int i = 0; i < 4; ++i)
        #pragma unroll
        for (int j = 0; j < 2; ++j) acc[i][j] = (f32x4){0.f, 0.f, 0.f, 0.f};

    float4 pa[4][2], pb[2][2];
    #pragma unroll
    for (int q = 0; q < 4; ++q) {
        pa[q][0] = *(const float4*)(aptr[q]);
        pa[q][1] = *(const float4*)(aptr[q] + 4);
    }
    #pragma unroll
    for (int q = 0; q < 2; ++q) {
        pb[q][0] = *(const float4*)(bptr[q]);
        pb[q][1] = *(const float4*)(bptr[q] + 4);
    }

    for (int ks = 0; ks < 4; ++ks) {
        __syncthreads();   // previous chunk's LDS reads done
        #pragma unroll
        for (int q = 0; q < 4; ++q) {
            const int r  = r0 + 32 * q;
            const int sw = (s ^ (r & 7)) << 2;
            uint4 wa = { pk_bf2(pa[q][0].x, pa[q][0].y), pk_bf2(pa[q][0].z, pa[q][0].w),
                         pk_bf2(pa[q][1].x, pa[q][1].y), pk_bf2(pa[q][1].z, pa[q][1].w) };
            *(uint4*)&A_s[r * 32 + sw] = wa;
        }
        #pragma unroll
        for (int q = 0; q < 2; ++q) {
            const int r  = r0 + 32 * q;
            const int sw = (s ^ (r & 7)) << 2;
            uint4 wb = { pk_bf2(pb[q][0].x, pb[q][0].y), pk_bf2(pb[q][0].z, pb[q][0].w),
                         pk_bf2(pb[q][1].x, pb[q][1].y), pk_bf2(pb[q][1].z, pb[q][1].w) };
            *(uint4*)&B_s[r * 32 + sw] = wb;
        }
        __syncthreads();
        if (ks < 3) {   // prefetch next fp32 chunk; consumed after next barrier
            const int off = (ks + 1) * 64;
            #pragma unroll
            for (int q = 0; q < 4; ++q) {
                pa[q][0] = *(const float4*)(aptr[q] + off);
                pa[q][1] = *(const float4*)(aptr[q] + off + 4);
            }
            #pragma unroll
            for (int q = 0; q < 2; ++q) {
                pb[q][0] = *(const float4*)(bptr[q] + off);
                pb[q][1] = *(const float4*)(bptr[q] + off + 4);
            }
        }
        #pragma unroll
        for (int kk = 0; kk < 2; ++kk) {
            short8 af[4], bfj[2];
            #pragma unroll
            for (int i = 0; i < 4; ++i) {
                const int r  = wr * 64 + i * 16 + rl;
                const int sl = (kk * 4 + g4) ^ (r & 7);
                af[i] = *(const short8*)&A_s[r * 32 + sl * 4];
            }
            #pragma unroll
            for (int j = 0; j < 2; ++j) {
                const int r  = wc * 32 + j * 16 + rl;
                const int sl = (kk * 4 + g4) ^ (r & 7);
                bfj[j] = *(const short8*)&B_s[r * 32 + sl * 4];
            }
            #pragma unroll
            for (int i = 0; i < 4; ++i)
                #pragma unroll
                for (int j = 0; j < 2; ++j)
                    acc[i][j] = __builtin_amdgcn_mfma_f32_16x16x32_bf16(af[i], bfj[j], acc[i][j], 0, 0, 0);
        }
    }

    // fused epilogue: e = exp(1 + c/128); row sums, col sums, Dpos/Ex1/Ex2 extraction
    float rs[4][4];
    float cs[2] = {0.f, 0.f};
    #pragma unroll
    for (int i = 0; i < 4; ++i)
        #pragma unroll
        for (int rg = 0; rg < 4; ++rg) rs[i][rg] = 0.f;

    #pragma unroll
    for (int i = 0; i < 4; ++i) {
        #pragma unroll
        for (int j = 0; j < 2; ++j) {
            const int kg = by * 64 + wc * 32 + j * 16 + rl;       // C/D: col = lane&15 [m89]
            #pragma unroll
            for (int rg = 0; rg < 4; ++rg) {
                const int pg = bx * 128 + wr * 64 + i * 16 + g4 * 4 + rg;  // row = (lane>>4)*4+reg
                const float c = acc[i][j][rg] * (1.f / 128.f);
                const float e = __expf(1.f + c);
                if (kg == pg) Dpos[pg] = c;            // M[p,p]
                if (kg == 2 * pg + 1) Ex1[pg] = e;     // T[p, 2p+1]
                if (pg == 2 * kg) Ex2[kg] = e;         // T[2k, k]
                rs[i][rg] += e;
                cs[j] += e;
            }
        }
    }

    // row reduction: over 16 cols (rl lanes), then across the 2 wc waves via LDS
    #pragma unroll
    for (int i = 0; i < 4; ++i) {
        #pragma unroll
        for (int rg = 0; rg < 4; ++rg) {
            float v = rs[i][rg];
            v += __shfl_xor(v, 1); v += __shfl_xor(v, 2);
            v += __shfl_xor(v, 4); v += __shfl_xor(v, 8);
            if (rl == 0) red[wc][wr * 64 + i * 16 + g4 * 4 + rg] = v;
        }
    }
    // col reduction: over 64 rows of the wave (g4 groups), then across wr waves
    #pragma unroll
    for (int j = 0; j < 2; ++j) {
        float v = cs[j];
        v += __shfl_xor(v, 16); v += __shfl_xor(v, 32);
        if (g4 == 0) red2[wr][wc * 32 + j * 16 + rl] = v;
    }
    __syncthreads();
    if (t < 128)
        Srow[by * PN + bx * 128 + t] = red[0][t] + red[1][t];
    else if (t < 192)
        Scol[bx * PN + by * 64 + (t - 128)] = red2[0][t - 128] + red2[1][t - 128];
}

__global__ __launch_bounds__(64) void sml_finish(
    const float* __restrict__ Srow, const float* __restrict__ Scol,
    const float* __restrict__ Dpos, const float* __restrict__ Ex1,
    const float* __restrict__ Ex2, float* __restrict__ out)
{
    const int t = threadIdx.x;
    const int p = blockIdx.x * 64 + t;
    float ssum = 0.f;
    #pragma unroll
    for (int g = 0; g < 32; ++g) ssum += Srow[g * PN + p];
    #pragma unroll
    for (int g = 0; g < 16; ++g) ssum += Scol[g * PN + p];
    if (p < 1024) ssum -= Ex1[p] + Ex2[p];
    const float J = __logf(1e-8f + ssum) - Dpos[p];
    const float v = fmaxf(J, 0.f);
    float local = v * v;
    #pragma unroll
    for (int m = 1; m < 64; m <<= 1) local += __shfl_xor(local, m);
    if (t == 0) atomicAdd(out, local * (1.f / 4096.f));
}

extern "C" void kernel_launch(void* const* d_in, const int* in_sizes, int n_in,
                              void* d_out, int out_size, void* d_ws, size_t ws_size,
                              hipStream_t stream) {
    const float* X = (const float*)d_in[0];
    float* ws   = (float*)d_ws;
    float* Srow = ws;                  // 32*2048
    float* Scol = Srow + 32 * PN;      // 16*2048
    float* Dpos = Scol + 16 * PN;      // 2048
    float* Ex1  = Dpos + PN;           // 2048
    float* Ex2  = Ex1 + PN;            // 2048
    float* out  = (float*)d_out;

    dim3 g1(16, 32);
    sml_mfma<<<g1, dim3(256), 0, stream>>>(X, Srow, Scol, Dpos, Ex1, Ex2, out);
    sml_finish<<<32, dim3(64), 0, stream>>>(Srow, Scol, Dpos, Ex1, Ex2, out);
}